// Round 1
// baseline (399.020 us; speedup 1.0000x reference)
//
#include <hip/hip_runtime.h>

// PatchGram: per (n, layer) block:
//  1) stage feat[n] (C*9 floats, contiguous) into LDS via float4 loads
//  2) channel-window mean -> fr[64][9]  (window i = channels [i*k,(i+1)*k), k=C/64)
//  3) gram[c][d] = (1/9) sum_p fr[c][p]*fr[d][p]; pool-4 along d -> out[c*16+dg]
// Combined scale on raw dots: 1/(9*4) = 1/36.

#define N_SAMPLES 6272

__global__ __launch_bounds__(256, 4) void patchgram_kernel(
    const float* __restrict__ f0, const float* __restrict__ f1,
    float* __restrict__ out)
{
    __shared__ float4 s4[2304];   // 36 KiB: raw tile, max C=1024 -> 9216 floats
    __shared__ float  fr[576];    // 64 rows x 9
    float* s = (float*)s4;

    const int bid   = blockIdx.x;
    const int n     = bid >> 1;
    const int layer = bid & 1;
    const int t     = threadIdx.x;

    const float* __restrict__ src = layer ? f1 : f0;
    const int C    = layer ? 1024 : 512;
    const int k    = C >> 6;          // 16 or 8
    const int nflt = C * 9;           // 9216 or 4608
    const int nv4  = nflt >> 2;       // 2304 or 1152

    // ---- stage to LDS (coalesced float4) ----
    const float4* __restrict__ g = (const float4*)(src + (size_t)n * nflt);
    for (int i = t; i < nv4; i += 256) s4[i] = g[i];
    __syncthreads();

    // ---- channel-window reduction: 576 (i,p) pairs ----
    const float rk = 1.0f / (float)k;
    for (int pair = t; pair < 576; pair += 256) {
        const int i = pair / 9;
        const int p = pair - i * 9;
        const float* base = s + i * k * 9 + p;
        float acc = 0.f;
        if (k == 8) {
#pragma unroll
            for (int cc = 0; cc < 8; ++cc) acc += base[cc * 9];
        } else {
#pragma unroll
            for (int cc = 0; cc < 16; ++cc) acc += base[cc * 9];
        }
        fr[pair] = acc * rk;
    }
    __syncthreads();

    // ---- gram + pool: thread owns c in [c0,c0+4), one d-group dg (4 d's) ----
    const int c0 = (t >> 4) << 2;     // 0,4,...,60
    const int dg = t & 15;            // 0..15

    float a[4][9];
#pragma unroll
    for (int i = 0; i < 4; ++i)
#pragma unroll
        for (int p = 0; p < 9; ++p) a[i][p] = fr[(c0 + i) * 9 + p];

    float acc[4] = {0.f, 0.f, 0.f, 0.f};
#pragma unroll
    for (int dd = 0; dd < 4; ++dd) {
        float b[9];
        const int d = dg * 4 + dd;
#pragma unroll
        for (int p = 0; p < 9; ++p) b[p] = fr[d * 9 + p];
#pragma unroll
        for (int i = 0; i < 4; ++i) {
            float s2 = 0.f;
#pragma unroll
            for (int p = 0; p < 9; ++p) s2 += a[i][p] * b[p];
            acc[i] += s2;
        }
    }

    float* __restrict__ o = out + ((size_t)n * 2 + layer) * 1024;
    const float scale = 1.0f / 36.0f;
#pragma unroll
    for (int i = 0; i < 4; ++i) o[(c0 + i) * 16 + dg] = acc[i] * scale;
}

extern "C" void kernel_launch(void* const* d_in, const int* in_sizes, int n_in,
                              void* d_out, int out_size, void* d_ws, size_t ws_size,
                              hipStream_t stream) {
    const float* f0 = (const float*)d_in[0];   // [6272, 512, 3, 3]
    const float* f1 = (const float*)d_in[1];   // [6272, 1024, 3, 3]
    float* out = (float*)d_out;                // [6272, 2, 1024]
    patchgram_kernel<<<N_SAMPLES * 2, 256, 0, stream>>>(f0, f1, out);
}

// Round 2
// 389.644 us; speedup vs baseline: 1.0241x; 1.0241x over previous
//
#include <hip/hip_runtime.h>

// PatchGram, restructured:
//  A) each thread reads 36 contiguous floats (9 float4) of its window and
//     accumulates the 9 spatial phases in registers (window = k*9 contiguous
//     floats; 36 | k*9, so phase indices are static). Lane butterfly over the
//     4 (C=1024) or 2 (C=512) lanes sharing a window -> fr[64][9] (unscaled),
//     stored to LDS padded to 12 floats/row for aligned float4 reads.
//  B) pooled rows B[dg][p] = sum_{dd<4} fr[4dg+dd][p]  (pooling is linear!)
//  C) out[c*16+dg] = scale * sum_p fr[c][p]*B[dg][p],  scale = 1/(36*k*k)
//     thread owns (c, 4 consecutive dg) -> one coalesced float4 store.

#define N_SAMPLES 6272

__global__ __launch_bounds__(256, 8) void patchgram_kernel(
    const float* __restrict__ f0, const float* __restrict__ f1,
    float* __restrict__ out)
{
    __shared__ float4 fr4[64 * 3];   // fr rows padded to 12 floats (48 B, 16B-aligned)
    __shared__ float4 B4[16 * 3];    // pooled rows, same padding
    float* fr = (float*)fr4;
    float* B  = (float*)B4;

    const int bid   = blockIdx.x;
    const int n     = bid >> 1;
    const int layer = bid & 1;
    const int t     = threadIdx.x;

    const float* __restrict__ src = layer ? f1 : f0;
    const int nflt   = layer ? 9216 : 4608;   // C*9
    const int nload  = nflt / 36;             // 256 or 128 active loader threads
    const int gshift = layer ? 2 : 1;         // lanes per window = 1<<gshift

    // ---- phase A: coalesced global read, per-phase register accumulate ----
    if (t < nload) {
        const float4* __restrict__ g =
            (const float4*)(src + (size_t)n * nflt) + t * 9;
        float4 v[9];
#pragma unroll
        for (int j = 0; j < 9; ++j) v[j] = g[j];

        float acc[9];
#pragma unroll
        for (int p = 0; p < 9; ++p) acc[p] = 0.f;
#pragma unroll
        for (int j = 0; j < 9; ++j) {
            acc[(4 * j + 0) % 9] += v[j].x;
            acc[(4 * j + 1) % 9] += v[j].y;
            acc[(4 * j + 2) % 9] += v[j].z;
            acc[(4 * j + 3) % 9] += v[j].w;
        }
        // butterfly across the lanes sharing this window
#pragma unroll
        for (int p = 0; p < 9; ++p) acc[p] += __shfl_xor(acc[p], 1);
        if (layer) {
#pragma unroll
            for (int p = 0; p < 9; ++p) acc[p] += __shfl_xor(acc[p], 2);
        }
        if ((t & ((1 << gshift) - 1)) == 0) {
            const int row = t >> gshift;      // 0..63
            fr4[row * 3 + 0] = make_float4(acc[0], acc[1], acc[2], acc[3]);
            fr4[row * 3 + 1] = make_float4(acc[4], acc[5], acc[6], acc[7]);
            fr4[row * 3 + 2] = make_float4(acc[8], 0.f, 0.f, 0.f);
        }
    }
    __syncthreads();

    // ---- phase B: pooled rows B[16][9] ----
    if (t < 144) {
        const int dg = t / 9;
        const int p  = t - dg * 9;
        B[dg * 12 + p] = fr[(4 * dg + 0) * 12 + p] + fr[(4 * dg + 1) * 12 + p] +
                         fr[(4 * dg + 2) * 12 + p] + fr[(4 * dg + 3) * 12 + p];
    }
    __syncthreads();

    // ---- phase C: out[c][dg] = scale * <fr[c], B[dg]> ----
    const int c   = t >> 2;                   // 0..63
    const int dgq = t & 3;                    // owns dg = 4*dgq .. 4*dgq+3
    const float4 a0 = fr4[c * 3 + 0];
    const float4 a1 = fr4[c * 3 + 1];
    const float4 a2 = fr4[c * 3 + 2];
    const int   k     = layer ? 16 : 8;
    const float scale = 1.0f / (36.0f * (float)(k * k));

    float4 o4;
    float* op = (float*)&o4;
#pragma unroll
    for (int j = 0; j < 4; ++j) {
        const int d = dgq * 4 + j;
        const float4 b0 = B4[d * 3 + 0];
        const float4 b1 = B4[d * 3 + 1];
        const float4 b2 = B4[d * 3 + 2];
        float s = a0.x * b0.x + a0.y * b0.y + a0.z * b0.z + a0.w * b0.w
                + a1.x * b1.x + a1.y * b1.y + a1.z * b1.z + a1.w * b1.w
                + a2.x * b2.x;                 // pad lanes unused
        op[j] = s * scale;
    }
    float4* o = (float4*)(out + ((size_t)n * 2 + layer) * 1024 + c * 16 + dgq * 4);
    *o = o4;
}

extern "C" void kernel_launch(void* const* d_in, const int* in_sizes, int n_in,
                              void* d_out, int out_size, void* d_ws, size_t ws_size,
                              hipStream_t stream) {
    const float* f0 = (const float*)d_in[0];   // [6272, 512, 3, 3]
    const float* f1 = (const float*)d_in[1];   // [6272, 1024, 3, 3]
    float* out = (float*)d_out;                // [6272, 2, 1024]
    patchgram_kernel<<<N_SAMPLES * 2, 256, 0, stream>>>(f0, f1, out);
}

// Round 3
// 387.980 us; speedup vs baseline: 1.0285x; 1.0043x over previous
//
#include <hip/hip_runtime.h>

// PatchGram, per-layer kernels:
//  A) coalesced global->LDS staging of the whole [C*9]-float sample tile via
//     global_load_lds (16B/lane, wave-uniform dst + lane*16 — loop index
//     i = t + 256*j keeps exactly that layout).
//  A2) window reduction: 2 (C=512) or 4 (C=1024) lanes per 64-window read
//     9 consecutive float4 each from LDS, accumulate the 9 spatial phases
//     (phase of (j,comp) = (4j+comp) mod 9), butterfly-combine via shfl_xor,
//     write fr[64][9] padded to 12 floats/row.
//  B) pooled rows B[dg] = sum_{dd<4} fr[4dg+dd]   (output pooling is linear)
//  C) out[c*16+dg] = 1/(36 k^2) * <fr[c], B[dg]>, coalesced float4 store.

#define N_SAMPLES 6272

typedef const __attribute__((address_space(1))) void* gas_ptr;
typedef __attribute__((address_space(3))) void* las_ptr;

__device__ __forceinline__ void load16_to_lds(const void* g, void* l) {
    __builtin_amdgcn_global_load_lds((gas_ptr)g, (las_ptr)l, 16, 0, 0);
}

template <int CH>
__global__ __launch_bounds__(256) void patchgram_layer(
    const float* __restrict__ src, float* __restrict__ out)
{
    constexpr int NF   = CH * 9;          // floats per sample tile
    constexpr int NV4  = NF / 4;          // float4s per tile (1152 / 2304)
    constexpr int GSH  = (CH == 1024) ? 2 : 1;   // log2(lanes per window)
    constexpr int NRED = 64 << GSH;       // reducer threads (128 / 256)
    constexpr int K    = CH / 64;
    constexpr float SCALE = 1.0f / (36.0f * (float)(K * K));

    __shared__ float4 tile[NV4];          // 18 or 36 KiB
    __shared__ float4 fr4[64 * 3];        // fr rows padded to 12 floats
    __shared__ float4 B4[16 * 3];

    const int n = blockIdx.x;
    const int t = threadIdx.x;

    // ---- A: coalesced staging ----
    const float4* __restrict__ g = (const float4*)(src + (size_t)n * NF);
    for (int i = t; i < NV4; i += 256)
        load16_to_lds(&g[i], &tile[i]);
    __syncthreads();   // drains vmcnt for global_load_lds

    // ---- A2: window reduction ----
    if (t < NRED) {
        const float4* __restrict__ tp = &tile[t * 9];
        float acc[9];
#pragma unroll
        for (int p = 0; p < 9; ++p) acc[p] = 0.f;
#pragma unroll
        for (int j = 0; j < 9; ++j) {
            const float4 v = tp[j];
            acc[(4 * j + 0) % 9] += v.x;
            acc[(4 * j + 1) % 9] += v.y;
            acc[(4 * j + 2) % 9] += v.z;
            acc[(4 * j + 3) % 9] += v.w;
        }
#pragma unroll
        for (int p = 0; p < 9; ++p) acc[p] += __shfl_xor(acc[p], 1);
        if (GSH == 2) {
#pragma unroll
            for (int p = 0; p < 9; ++p) acc[p] += __shfl_xor(acc[p], 2);
        }
        if ((t & ((1 << GSH) - 1)) == 0) {
            const int row = t >> GSH;     // 0..63
            fr4[row * 3 + 0] = make_float4(acc[0], acc[1], acc[2], acc[3]);
            fr4[row * 3 + 1] = make_float4(acc[4], acc[5], acc[6], acc[7]);
            fr4[row * 3 + 2] = make_float4(acc[8], 0.f, 0.f, 0.f);
        }
    }
    __syncthreads();

    // ---- B: pooled rows ----
    if (t < 144) {
        const int dg = t / 9;
        const int p  = t - dg * 9;
        const float* fr = (const float*)fr4;
        ((float*)B4)[dg * 12 + p] =
            fr[(4 * dg + 0) * 12 + p] + fr[(4 * dg + 1) * 12 + p] +
            fr[(4 * dg + 2) * 12 + p] + fr[(4 * dg + 3) * 12 + p];
    }
    __syncthreads();

    // ---- C: out[c][dg] = SCALE * <fr[c], B[dg]> ----
    const int c   = t >> 2;               // 0..63
    const int dgq = t & 3;                // dg group of 4
    const float4 a0 = fr4[c * 3 + 0];
    const float4 a1 = fr4[c * 3 + 1];
    const float4 a2 = fr4[c * 3 + 2];

    float4 o4;
    float* op = (float*)&o4;
#pragma unroll
    for (int j = 0; j < 4; ++j) {
        const int d = dgq * 4 + j;
        const float4 b0 = B4[d * 3 + 0];
        const float4 b1 = B4[d * 3 + 1];
        const float4 b2 = B4[d * 3 + 2];
        float s = a0.x * b0.x + a0.y * b0.y + a0.z * b0.z + a0.w * b0.w
                + a1.x * b1.x + a1.y * b1.y + a1.z * b1.z + a1.w * b1.w
                + a2.x * b2.x;
        op[j] = s * SCALE;
    }
    float4* o = (float4*)(out + (size_t)n * 2048 + c * 16 + dgq * 4);
    *o = o4;
}

extern "C" void kernel_launch(void* const* d_in, const int* in_sizes, int n_in,
                              void* d_out, int out_size, void* d_ws, size_t ws_size,
                              hipStream_t stream) {
    const float* f0 = (const float*)d_in[0];   // [6272, 512, 3, 3]
    const float* f1 = (const float*)d_in[1];   // [6272, 1024, 3, 3]
    float* out = (float*)d_out;                // [6272, 2, 1024]
    patchgram_layer<512><<<N_SAMPLES, 256, 0, stream>>>(f0, out);
    patchgram_layer<1024><<<N_SAMPLES, 256, 0, stream>>>(f1, out + 1024);
}